// Round 1
// baseline (72.515 us; speedup 1.0000x reference)
//
#include <hip/hip_runtime.h>

typedef __attribute__((ext_vector_type(8))) short short8v;
typedef __attribute__((ext_vector_type(4))) short short4v;
typedef __attribute__((ext_vector_type(4))) float float4v;

// fp32 -> bf16 round-to-nearest-even (bit twiddle; NaN irrelevant for this data)
__device__ __forceinline__ short f2bf(float f) {
  union { float f; unsigned int u; } v;
  v.f = f;
  unsigned int u = v.u;
  u += 0x7fffu + ((u >> 16) & 1u);
  return (short)(u >> 16);
}

// Load 8 contiguous f32 and convert to a bf16x8 MFMA fragment.
__device__ __forceinline__ short8v load_frag8(const float* __restrict__ p) {
  float4 a = *reinterpret_cast<const float4*>(p);
  float4 b = *reinterpret_cast<const float4*>(p + 4);
  short8v r;
  r[0] = f2bf(a.x); r[1] = f2bf(a.y); r[2] = f2bf(a.z); r[3] = f2bf(a.w);
  r[4] = f2bf(b.x); r[5] = f2bf(b.y); r[6] = f2bf(b.z); r[7] = f2bf(b.w);
  return r;
}

// One wave handles one row m. Grid = 2048 blocks x 256 threads = 8192 waves.
// Stage 1: C1[a][q] = sum_b X[m,a,b]*B[q,b]      (16 MFMAs, A-op from global x)
//          -> write C1 transposed (Y1T[q][a], bf16, XOR-swizzled) to per-wave LDS
// Stage 2: C2T[q][p] = sum_a Y1T[q][a]*A[p][a]   (16 MFMAs, A-op from LDS)
//          -> lane holds 4 consecutive output cols -> float4 bias + float4 store
__global__ __launch_bounds__(256, 4)
void kron64_kernel(const float* __restrict__ x, const float* __restrict__ A,
                   const float* __restrict__ B, const float* __restrict__ bias,
                   float* __restrict__ out) {
  __shared__ short y1[4][4096];  // 4 waves x 64x64 bf16 (Y1^T), 32 KB total

  const int tid = threadIdx.x;
  const int w = tid >> 6;       // wave in block
  const int lane = tid & 63;
  const int g = lane >> 4;      // lane group 0..3
  const int c = lane & 15;      // lane-in-group 0..15
  const int m = blockIdx.x * 4 + w;
  const int swz = (c & 7) << 3; // element-index XOR swizzle (bytes: (q&7)<<4)

  short* yw = y1[w];
  const float* xm = x + (size_t)m * 4096;
  const float4v vzero = {0.f, 0.f, 0.f, 0.f};

  // ---------------- Stage 1 ----------------
  {
    // B-operand fragments of C1 = X * B^T: frag(qt,kk)[i] = B[16qt+c][32kk+8g+i]
    short8v bfrag[4][2];
#pragma unroll
    for (int qt = 0; qt < 4; ++qt)
#pragma unroll
      for (int kk = 0; kk < 2; ++kk)
        bfrag[qt][kk] = load_frag8(B + (16 * qt + c) * 64 + 32 * kk + 8 * g);

#pragma unroll
    for (int at = 0; at < 4; ++at) {
      float4v acc[4];
#pragma unroll
      for (int qt = 0; qt < 4; ++qt) acc[qt] = vzero;

#pragma unroll
      for (int kk = 0; kk < 2; ++kk) {
        // A-operand: X[m][16at+c][32kk+8g .. +7] (8 contiguous f32)
        short8v xfrag = load_frag8(xm + (16 * at + c) * 64 + 32 * kk + 8 * g);
#pragma unroll
        for (int qt = 0; qt < 4; ++qt)
          acc[qt] = __builtin_amdgcn_mfma_f32_16x16x32_bf16(
              xfrag, bfrag[qt][kk], acc[qt], 0, 0, 0);
      }
      // D tile (at,qt): lane holds C1[16at+4g+b][16qt+c], b=0..3.
      // Store transposed: Y1T[q][a] with a = 16at+4g+b consecutive -> short4.
#pragma unroll
      for (int qt = 0; qt < 4; ++qt) {
        short4v v;
        v[0] = f2bf(acc[qt][0]); v[1] = f2bf(acc[qt][1]);
        v[2] = f2bf(acc[qt][2]); v[3] = f2bf(acc[qt][3]);
        int idx = ((16 * qt + c) * 64 + 16 * at + 4 * g) ^ swz;
        *reinterpret_cast<short4v*>(&yw[idx]) = v;
      }
    }
  }

  __syncthreads();  // order LDS writes before reads (cheap: once per kernel)

  // ---------------- Stage 2 ----------------
  {
    // A-operand: Y1T rows (contiguous in a after transpose) via b128 reads
    short8v yfrag[4][2];
#pragma unroll
    for (int qt = 0; qt < 4; ++qt)
#pragma unroll
      for (int kk = 0; kk < 2; ++kk) {
        int idx = (((16 * qt + c) * 64) + 32 * kk + 8 * g) ^ swz;
        yfrag[qt][kk] = *reinterpret_cast<const short8v*>(&yw[idx]);
      }
    // B-operand: A^T[a][p] = A[p][a]: frag(pt,kk)[i] = A[16pt+c][32kk+8g+i]
    short8v afrag[4][2];
#pragma unroll
    for (int pt = 0; pt < 4; ++pt)
#pragma unroll
      for (int kk = 0; kk < 2; ++kk)
        afrag[pt][kk] = load_frag8(A + (16 * pt + c) * 64 + 32 * kk + 8 * g);

    float* om = out + (size_t)m * 4096;
#pragma unroll
    for (int pt = 0; pt < 4; ++pt) {
#pragma unroll
      for (int qt = 0; qt < 4; ++qt) {
        float4v acc = vzero;
#pragma unroll
        for (int kk = 0; kk < 2; ++kk)
          acc = __builtin_amdgcn_mfma_f32_16x16x32_bf16(
              yfrag[qt][kk], afrag[pt][kk], acc, 0, 0, 0);
        // D tile: lane holds C2T[16qt+4g+b][16pt+c] = C2[p][q],
        // p = 16pt+c, q = 16qt+4g+b -> n = p*64+q consecutive in b.
        int n = (16 * pt + c) * 64 + 16 * qt + 4 * g;
        float4 bv = *reinterpret_cast<const float4*>(bias + n);
        float4 o;
        o.x = acc[0] + bv.x;
        o.y = acc[1] + bv.y;
        o.z = acc[2] + bv.z;
        o.w = acc[3] + bv.w;
        *reinterpret_cast<float4*>(om + n) = o;
      }
    }
  }
}

extern "C" void kernel_launch(void* const* d_in, const int* in_sizes, int n_in,
                              void* d_out, int out_size, void* d_ws, size_t ws_size,
                              hipStream_t stream) {
  (void)in_sizes; (void)n_in; (void)out_size; (void)d_ws; (void)ws_size;
  const float* x    = (const float*)d_in[0];
  const float* A    = (const float*)d_in[1];
  const float* B    = (const float*)d_in[2];
  const float* bias = (const float*)d_in[3];
  float* out = (float*)d_out;

  dim3 grid(2048), block(256);
  hipLaunchKernelGGL(kron64_kernel, grid, block, 0, stream, x, A, B, bias, out);
}

// Round 3
// 63.451 us; speedup vs baseline: 1.1429x; 1.1429x over previous
//
#include <hip/hip_runtime.h>

typedef __attribute__((ext_vector_type(8))) short short8v;
typedef __attribute__((ext_vector_type(4))) short short4v;
typedef __attribute__((ext_vector_type(4))) float float4v;

// fp32 -> bf16 via native cast: compiler emits v_cvt_pk_bf16_f32 (RNE).
__device__ __forceinline__ short f2bf(float f) {
  __bf16 h = (__bf16)f;
  return __builtin_bit_cast(short, h);
}

// Load 8 contiguous f32 and convert to a bf16x8 MFMA fragment.
__device__ __forceinline__ short8v load_frag8(const float* __restrict__ p) {
  float4 a = *reinterpret_cast<const float4*>(p);
  float4 b = *reinterpret_cast<const float4*>(p + 4);
  short8v r;
  r[0] = f2bf(a.x); r[1] = f2bf(a.y); r[2] = f2bf(a.z); r[3] = f2bf(a.w);
  r[4] = f2bf(b.x); r[5] = f2bf(b.y); r[6] = f2bf(b.z); r[7] = f2bf(b.w);
  return r;
}

constexpr int ROWS = 4;  // rows of x per wave

// One wave handles ROWS rows. Grid = 8192/(4*ROWS) = 512 blocks x 256 thr.
// Weights (A,B) + bias live in registers for the whole wave; bias is folded
// into the stage-2 accumulator init. Y1^T bounces through per-wave LDS
// (double-buffered, XOR-swizzled); no __syncthreads — wave-local lgkmcnt
// fence only, so waves stay fully independent.
__global__ __launch_bounds__(256, 2)
void kron64_kernel(const float* __restrict__ x, const float* __restrict__ A,
                   const float* __restrict__ B, const float* __restrict__ bias,
                   float* __restrict__ out) {
  __shared__ short y1[4][2][4096];  // 4 waves x 2 bufs x 64x64 bf16 = 64 KB

  const int tid = threadIdx.x;
  const int w = tid >> 6;
  const int lane = tid & 63;
  const int g = lane >> 4;      // lane group 0..3
  const int c = lane & 15;      // lane-in-group 0..15
  const int swz = (c & 7) << 3; // element-index XOR swizzle
  const int m0 = (blockIdx.x * 4 + w) * ROWS;

  // ---- persistent per-wave state: B,A fragments + bias (in D-layout) ----
  short8v bfrag[4][2];  // frag(qt,kk)[i] = B[16qt+c][32kk+8g+i]
  short8v afrag[4][2];  // frag(pt,kk)[i] = A[16pt+c][32kk+8g+i]
  float4v biasf[4][4];  // tile (pt,qt): bias[(16pt+c)*64 + 16qt+4g .. +3]
#pragma unroll
  for (int t = 0; t < 4; ++t)
#pragma unroll
    for (int kk = 0; kk < 2; ++kk) {
      bfrag[t][kk] = load_frag8(B + (16 * t + c) * 64 + 32 * kk + 8 * g);
      afrag[t][kk] = load_frag8(A + (16 * t + c) * 64 + 32 * kk + 8 * g);
    }
#pragma unroll
  for (int pt = 0; pt < 4; ++pt)
#pragma unroll
    for (int qt = 0; qt < 4; ++qt) {
      float4 bv = *reinterpret_cast<const float4*>(
          bias + (16 * pt + c) * 64 + 16 * qt + 4 * g);
      float4v t; t[0] = bv.x; t[1] = bv.y; t[2] = bv.z; t[3] = bv.w;
      biasf[pt][qt] = t;
    }

  const float4v vzero = {0.f, 0.f, 0.f, 0.f};

  auto body = [&](int r, short* yw) {
    const float* xm = x + (size_t)(m0 + r) * 4096;
    // ---------------- Stage 1: C1 = Xm * B^T ----------------
#pragma unroll
    for (int at = 0; at < 4; ++at) {
      float4v acc[4];
#pragma unroll
      for (int qt = 0; qt < 4; ++qt) acc[qt] = vzero;
#pragma unroll
      for (int kk = 0; kk < 2; ++kk) {
        short8v xfrag = load_frag8(xm + (16 * at + c) * 64 + 32 * kk + 8 * g);
#pragma unroll
        for (int qt = 0; qt < 4; ++qt)
          acc[qt] = __builtin_amdgcn_mfma_f32_16x16x32_bf16(
              xfrag, bfrag[qt][kk], acc[qt], 0, 0, 0);
      }
      // lane holds C1[16at+4g+b][16qt+c]; store transposed Y1T[q][a], swizzled
#pragma unroll
      for (int qt = 0; qt < 4; ++qt) {
        short4v v;
        v[0] = f2bf(acc[qt][0]); v[1] = f2bf(acc[qt][1]);
        v[2] = f2bf(acc[qt][2]); v[3] = f2bf(acc[qt][3]);
        int idx = ((16 * qt + c) * 64 + 16 * at + 4 * g) ^ swz;
        *reinterpret_cast<short4v*>(&yw[idx]) = v;
      }
    }

    // Wave-local fence: order the transpose writes before the reads.
    // (DS pipe is in-order per wave; this pins compiler ordering + drains.)
    __asm__ volatile("s_waitcnt lgkmcnt(0)" ::: "memory");

    // ---------------- Stage 2: C2^T = Y1^T * A^T ----------------
    short8v yfrag[4][2];
#pragma unroll
    for (int qt = 0; qt < 4; ++qt)
#pragma unroll
      for (int kk = 0; kk < 2; ++kk) {
        int idx = (((16 * qt + c) * 64) + 32 * kk + 8 * g) ^ swz;
        yfrag[qt][kk] = *reinterpret_cast<const short8v*>(&yw[idx]);
      }

    float* om = out + (size_t)(m0 + r) * 4096;
#pragma unroll
    for (int pt = 0; pt < 4; ++pt) {
#pragma unroll
      for (int qt = 0; qt < 4; ++qt) {
        float4v acc = biasf[pt][qt];  // bias folded into accumulator init
#pragma unroll
        for (int kk = 0; kk < 2; ++kk)
          acc = __builtin_amdgcn_mfma_f32_16x16x32_bf16(
              yfrag[qt][kk], afrag[pt][kk], acc, 0, 0, 0);
        // lane holds C2[p=16pt+c][q=16qt+4g+b] -> n = p*64+q consecutive in b
        int n = (16 * pt + c) * 64 + 16 * qt + 4 * g;
        float4v o = acc;
        __builtin_nontemporal_store(o, reinterpret_cast<float4v*>(om + n));
      }
    }
  };

  // Two half-iterations per loop so buffer parity is compile-time constant
  // and the scheduler can overlap row r+1's x-loads with row r's stage 2.
  for (int rr = 0; rr < ROWS / 2; ++rr) {
    body(2 * rr + 0, &y1[w][0][0]);
    body(2 * rr + 1, &y1[w][1][0]);
  }
}

extern "C" void kernel_launch(void* const* d_in, const int* in_sizes, int n_in,
                              void* d_out, int out_size, void* d_ws, size_t ws_size,
                              hipStream_t stream) {
  (void)in_sizes; (void)n_in; (void)out_size; (void)d_ws; (void)ws_size;
  const float* x    = (const float*)d_in[0];
  const float* A    = (const float*)d_in[1];
  const float* B    = (const float*)d_in[2];
  const float* bias = (const float*)d_in[3];
  float* out = (float*)d_out;

  dim3 grid(512), block(256);
  hipLaunchKernelGGL(kron64_kernel, grid, block, 0, stream, x, A, B, bias, out);
}